// Round 5
// 1848.657 us; speedup vs baseline: 1.0790x; 1.0790x over previous
//
#include <hip/hip_runtime.h>
#include <hip/hip_bf16.h>
#include <math.h>

// ---- problem constants ----
#define B_      8
#define M_      8192
#define E_      128
#define EPL     64
#define BM_     (B_ * M_)      // 65536 beats
#define BEAT_D  256
#define EP_D    384
#define RHY_D   128
#define DAY_D   512
#define NCODES  512
#define CODE_D  64
#define TOK_H   512
#define WINF    246
#define KP1     256            // padded K for G1 (246 -> 256)

// out layout (floats)
#define OFF_DAY   33554432L
#define OFF_EPCTX 33558528L
#define OFF_CODE  34082816L
#define OFF_VQ    34148352L

typedef unsigned short ushort_t;
typedef __attribute__((ext_vector_type(8))) short short8;
typedef __attribute__((ext_vector_type(4))) float floatx4;

__device__ __forceinline__ float gelu_t(float x) {
  float x3 = x * x * x;
  return 0.5f * x * (1.0f + tanhf(0.7978845608028654f * (x + 0.044715f * x3)));
}

__device__ __forceinline__ ushort_t f2bf(float f) {
  union { float f; unsigned u; } x; x.f = f;
  unsigned r = (x.u + 0x7fffu + ((x.u >> 16) & 1u)) >> 16;
  return (ushort_t)r;
}
__device__ __forceinline__ float bf2f(ushort_t u) {
  union { unsigned u; float f; } x; x.u = ((unsigned)u) << 16;
  return x.f;
}

// ======================= fp32 GEMM (small shapes) =======================
// A-source gather modes (fp32): 0: plain row-major, 3: ep_wave|ep_rhy
template<int AMODE>
__device__ __forceinline__ float load_A(const float* __restrict__ A,
                                        const float* __restrict__ A2,
                                        int m, int k, int K) {
  if (AMODE == 0) {
    return A[(long)m * K + k];
  } else {
    if (k < 384) return A[(long)m * 384 + k];
    return A2[(long)m * 128 + (k - 384)];
  }
}

// Small fp32 GEMM: tile 128x64, 8x4/thread. Used for G3/E2/E3/E4.
template<int AMODE, bool DOGELU, bool HASBIAS, bool EPMASK>
__global__ __launch_bounds__(256) void gemm_k(
    const float* __restrict__ A, const float* __restrict__ A2,
    const int* __restrict__ neps,
    const float* __restrict__ Bm, const float* __restrict__ bias,
    float* __restrict__ C, int M, int N, int K)
{
  __shared__ __align__(16) float As[16][132];
  __shared__ __align__(16) float Bs[16][68];

  const int bn = blockIdx.x * 64;
  const int bm = blockIdx.y * 128;
  const int tid = threadIdx.x;
  const int tx = tid & 15;
  const int ty = tid >> 4;

  float acc[8][4];
#pragma unroll
  for (int i = 0; i < 8; ++i)
#pragma unroll
    for (int j = 0; j < 4; ++j) acc[i][j] = 0.f;

  for (int k0 = 0; k0 < K; k0 += 16) {
    {
      int kk = tid & 15, r0 = tid >> 4;
      int gk = k0 + kk;
      bool kin = (gk < K);
#pragma unroll
      for (int i = 0; i < 8; ++i) {
        int row = r0 + i * 16;
        As[kk][row] = kin ? load_A<AMODE>(A, A2, bm + row, gk, K) : 0.f;
      }
    }
    {
      int c = tid & 63, r0 = tid >> 6;
#pragma unroll
      for (int i = 0; i < 4; ++i) {
        int kk = r0 + i * 4;
        int gk = k0 + kk;
        Bs[kk][c] = (gk < K) ? Bm[(long)gk * N + bn + c] : 0.f;
      }
    }
    __syncthreads();
#pragma unroll
    for (int kk = 0; kk < 16; ++kk) {
      float4 a0 = *reinterpret_cast<const float4*>(&As[kk][ty * 8]);
      float4 a1 = *reinterpret_cast<const float4*>(&As[kk][ty * 8 + 4]);
      float4 bv = *reinterpret_cast<const float4*>(&Bs[kk][tx * 4]);
      float av[8] = {a0.x, a0.y, a0.z, a0.w, a1.x, a1.y, a1.z, a1.w};
      float bb[4] = {bv.x, bv.y, bv.z, bv.w};
#pragma unroll
      for (int i = 0; i < 8; ++i)
#pragma unroll
        for (int j = 0; j < 4; ++j) acc[i][j] += av[i] * bb[j];
    }
    __syncthreads();
  }

#pragma unroll
  for (int i = 0; i < 8; ++i) {
    int gm = bm + ty * 8 + i;
    bool valid = true;
    if (EPMASK) valid = ((gm & (E_ - 1)) < neps[gm >> 7]);
    float4 o;
    float* op = &o.x;
#pragma unroll
    for (int j = 0; j < 4; ++j) {
      int gn = bn + tx * 4 + j;
      float v = acc[i][j];
      if (HASBIAS) v += bias[gn];
      if (DOGELU) v = gelu_t(v);
      if (EPMASK && !valid) v = 0.f;
      op[j] = v;
    }
    *reinterpret_cast<float4*>(&C[(long)gm * N + bn + tx * 4]) = o;
  }
}

// ======================= bf16 MFMA GEMM =======================
// C(MxN) = epi(A(MxK)_bf16 @ BT(NxK)_bf16 + bias). M%128==0, N%128==0, K%32==0.
// tile 128x128, 4 waves (2x2), each wave 64x64 via 4x4 mfma_f32_16x16x32_bf16.
// AMODE: 0 plain A; 1 concat [BEh(256)|CTXh(384)|RHYh(128)] (k0 never straddles).
// OUTM: 0 -> bf16 Ch; 1 -> fp32 C.
template<int AMODE, bool DOGELU, bool BEATMASK, int OUTM>
__global__ __launch_bounds__(256) void gemm_bf16(
    const ushort_t* __restrict__ A, const ushort_t* __restrict__ A2,
    const ushort_t* __restrict__ A3, const int* __restrict__ neps,
    const ushort_t* __restrict__ BT, const float* __restrict__ bias,
    float* __restrict__ C, ushort_t* __restrict__ Ch, int N, int K)
{
  __shared__ __align__(16) ushort_t As[128 * 40 + 8];
  __shared__ __align__(16) ushort_t Bs[128 * 40 + 8];

  const int bn = blockIdx.x * 128;
  const int bm = blockIdx.y * 128;
  const int tid = threadIdx.x;
  const int lane = tid & 63;
  const int wave = tid >> 6;
  const int wm = wave & 1;
  const int wn = wave >> 1;
  const int lm = lane & 15;
  const int q  = lane >> 4;

  floatx4 acc[4][4];
#pragma unroll
  for (int i = 0; i < 4; ++i)
#pragma unroll
    for (int j = 0; j < 4; ++j) acc[i][j] = (floatx4)0.f;

  for (int k0 = 0; k0 < K; k0 += 32) {
    const ushort_t* srcA; int ldA, cA;
    if (AMODE == 0) { srcA = A; ldA = K; cA = k0; }
    else {
      if (k0 < 256)      { srcA = A;  ldA = 256; cA = k0; }
      else if (k0 < 640) { srcA = A2; ldA = 384; cA = k0 - 256; }
      else               { srcA = A3; ldA = 128; cA = k0 - 640; }
    }
#pragma unroll
    for (int i = 0; i < 2; ++i) {
      int c = tid + i * 256;
      int r = c >> 2, h = c & 3;
      float4 v = *reinterpret_cast<const float4*>(&srcA[(long)(bm + r) * ldA + cA + h * 8]);
      *reinterpret_cast<float4*>(&As[r * 40 + h * 8]) = v;
    }
#pragma unroll
    for (int i = 0; i < 2; ++i) {
      int c = tid + i * 256;
      int r = c >> 2, h = c & 3;
      float4 v = *reinterpret_cast<const float4*>(&BT[(long)(bn + r) * K + k0 + h * 8]);
      *reinterpret_cast<float4*>(&Bs[r * 40 + h * 8]) = v;
    }
    __syncthreads();

    short8 af[4], bf[4];
#pragma unroll
    for (int i = 0; i < 4; ++i) {
      int mr = wm * 64 + i * 16 + lm;
      af[i] = *reinterpret_cast<const short8*>(&As[mr * 40 + q * 8]);
      int nr = wn * 64 + i * 16 + lm;
      bf[i] = *reinterpret_cast<const short8*>(&Bs[nr * 40 + q * 8]);
    }
#pragma unroll
    for (int i = 0; i < 4; ++i)
#pragma unroll
      for (int j = 0; j < 4; ++j)
        acc[i][j] = __builtin_amdgcn_mfma_f32_16x16x32_bf16(af[i], bf[j], acc[i][j], 0, 0, 0);
    __syncthreads();
  }

  // epilogue: C/D layout col = lane&15, row = q*4 + reg  [m89]
#pragma unroll
  for (int j = 0; j < 4; ++j) {
    int gn = bn + wn * 64 + j * 16 + lm;
    float bv = bias[gn];
#pragma unroll
    for (int i = 0; i < 4; ++i) {
#pragma unroll
      for (int r = 0; r < 4; ++r) {
        int gm = bm + wm * 64 + i * 16 + q * 4 + r;
        float v = acc[i][j][r] + bv;
        if (DOGELU) v = gelu_t(v);
        if (BEATMASK) {
          bool ok = (gm & (M_ - 1)) < neps[gm >> 13] * EPL;
          if (!ok) v = 0.f;
        }
        if (OUTM == 0) Ch[(long)gm * N + gn] = f2bf(v);
        else           C[(long)gm * N + gn] = v;
      }
    }
  }
}

// ======================= split-bf16 (3-plane, 6-product) MFMA GEMM =======================
// fp32-class precision on the matrix pipe:
//   x = xh + xm + xl (residual <= 2^-27);  C = hh + hm + mh + hl + mm + lh
// omitted terms (ml, lm, ll) <= ~2^-26 relative.
// OUTM 0: write THREE bf16 planes Oh/Om/Ol (stride N)            [G1]
// OUTM 2: write fp32 C (stride N) + bf16 Ch (stride N)           [G2]
template<bool DOGELU, int OUTM>
__global__ __launch_bounds__(256) void gemm_split6(
    const ushort_t* __restrict__ Ah, const ushort_t* __restrict__ Am,
    const ushort_t* __restrict__ Al,
    const ushort_t* __restrict__ BTh, const ushort_t* __restrict__ BTm,
    const ushort_t* __restrict__ BTl,
    const float* __restrict__ bias,
    ushort_t* __restrict__ Oh, ushort_t* __restrict__ Om, ushort_t* __restrict__ Ol,
    float* __restrict__ C, ushort_t* __restrict__ Ch,
    int N, int K)
{
  __shared__ __align__(16) ushort_t Ash[128 * 40];
  __shared__ __align__(16) ushort_t Asm[128 * 40];
  __shared__ __align__(16) ushort_t Asl[128 * 40];
  __shared__ __align__(16) ushort_t Bsh[128 * 40];
  __shared__ __align__(16) ushort_t Bsm[128 * 40];
  __shared__ __align__(16) ushort_t Bsl[128 * 40];

  const int bn = blockIdx.x * 128;
  const int bm = blockIdx.y * 128;
  const int tid = threadIdx.x;
  const int lane = tid & 63;
  const int wave = tid >> 6;
  const int wm = wave & 1;
  const int wn = wave >> 1;
  const int lm = lane & 15;
  const int q  = lane >> 4;

  floatx4 acc[4][4];
#pragma unroll
  for (int i = 0; i < 4; ++i)
#pragma unroll
    for (int j = 0; j < 4; ++j) acc[i][j] = (floatx4)0.f;

  for (int k0 = 0; k0 < K; k0 += 32) {
#pragma unroll
    for (int i = 0; i < 2; ++i) {
      int c = tid + i * 256;
      int r = c >> 2, h = c & 3;
      long aoff = (long)(bm + r) * K + k0 + h * 8;
      long boff = (long)(bn + r) * K + k0 + h * 8;
      *reinterpret_cast<float4*>(&Ash[r * 40 + h * 8]) =
          *reinterpret_cast<const float4*>(&Ah[aoff]);
      *reinterpret_cast<float4*>(&Asm[r * 40 + h * 8]) =
          *reinterpret_cast<const float4*>(&Am[aoff]);
      *reinterpret_cast<float4*>(&Asl[r * 40 + h * 8]) =
          *reinterpret_cast<const float4*>(&Al[aoff]);
      *reinterpret_cast<float4*>(&Bsh[r * 40 + h * 8]) =
          *reinterpret_cast<const float4*>(&BTh[boff]);
      *reinterpret_cast<float4*>(&Bsm[r * 40 + h * 8]) =
          *reinterpret_cast<const float4*>(&BTm[boff]);
      *reinterpret_cast<float4*>(&Bsl[r * 40 + h * 8]) =
          *reinterpret_cast<const float4*>(&BTl[boff]);
    }
    __syncthreads();

    short8 ah[4], am[4], al[4];
#pragma unroll
    for (int i = 0; i < 4; ++i) {
      int mr = wm * 64 + i * 16 + lm;
      ah[i] = *reinterpret_cast<const short8*>(&Ash[mr * 40 + q * 8]);
      am[i] = *reinterpret_cast<const short8*>(&Asm[mr * 40 + q * 8]);
      al[i] = *reinterpret_cast<const short8*>(&Asl[mr * 40 + q * 8]);
    }
#pragma unroll
    for (int j = 0; j < 4; ++j) {
      int nr = wn * 64 + j * 16 + lm;
      short8 bh = *reinterpret_cast<const short8*>(&Bsh[nr * 40 + q * 8]);
      short8 bmid = *reinterpret_cast<const short8*>(&Bsm[nr * 40 + q * 8]);
      short8 bl = *reinterpret_cast<const short8*>(&Bsl[nr * 40 + q * 8]);
#pragma unroll
      for (int i = 0; i < 4; ++i) {
        acc[i][j] = __builtin_amdgcn_mfma_f32_16x16x32_bf16(ah[i], bh,   acc[i][j], 0, 0, 0);
        acc[i][j] = __builtin_amdgcn_mfma_f32_16x16x32_bf16(ah[i], bmid, acc[i][j], 0, 0, 0);
        acc[i][j] = __builtin_amdgcn_mfma_f32_16x16x32_bf16(am[i], bh,   acc[i][j], 0, 0, 0);
        acc[i][j] = __builtin_amdgcn_mfma_f32_16x16x32_bf16(ah[i], bl,   acc[i][j], 0, 0, 0);
        acc[i][j] = __builtin_amdgcn_mfma_f32_16x16x32_bf16(am[i], bmid, acc[i][j], 0, 0, 0);
        acc[i][j] = __builtin_amdgcn_mfma_f32_16x16x32_bf16(al[i], bh,   acc[i][j], 0, 0, 0);
      }
    }
    __syncthreads();
  }

#pragma unroll
  for (int j = 0; j < 4; ++j) {
    int gn = bn + wn * 64 + j * 16 + lm;
    float bv = bias[gn];
#pragma unroll
    for (int i = 0; i < 4; ++i) {
#pragma unroll
      for (int r = 0; r < 4; ++r) {
        int gm = bm + wm * 64 + i * 16 + q * 4 + r;
        float v = acc[i][j][r] + bv;
        if (DOGELU) v = gelu_t(v);
        if (OUTM == 0) {
          ushort_t h = f2bf(v);  float r1 = v - bf2f(h);
          ushort_t mq = f2bf(r1); float r2 = r1 - bf2f(mq);
          Oh[(long)gm * N + gn] = h;
          Om[(long)gm * N + gn] = mq;
          Ol[(long)gm * N + gn] = f2bf(r2);
        } else {
          C[(long)gm * N + gn] = v;
          Ch[(long)gm * N + gn] = f2bf(v);
        }
      }
    }
  }
}

// split [windows|metadata] -> 3 bf16 planes (BM_, 256), cols 246..255 = 0
__global__ __launch_bounds__(256) void split_x3_k(
    const float* __restrict__ win, const float* __restrict__ meta,
    ushort_t* __restrict__ Xh, ushort_t* __restrict__ Xm, ushort_t* __restrict__ Xl)
{
  int i = blockIdx.x * 256 + threadIdx.x;   // over BM_ * 256
  int m = i >> 8, k = i & 255;
  float v = 0.f;
  if (k < 240)      v = win[(long)m * 240 + k];
  else if (k < 246) v = meta[(long)m * 6 + (k - 240)];
  ushort_t h = f2bf(v);  float r1 = v - bf2f(h);
  ushort_t mm = f2bf(r1); float r2 = r1 - bf2f(mm);
  Xh[i] = h; Xm[i] = mm; Xl[i] = f2bf(r2);
}

// transpose + 3-plane split: w (K,N) fp32 -> wTh/m/l (N,Kp) bf16, zero-pad k>=K
__global__ void wsplit3_k(const float* __restrict__ w,
                          ushort_t* __restrict__ wTh, ushort_t* __restrict__ wTm,
                          ushort_t* __restrict__ wTl, int K, int N, int Kp)
{
  int id = blockIdx.x * blockDim.x + threadIdx.x;
  if (id >= N * Kp) return;
  int n = id / Kp, k = id - n * Kp;
  float v = (k < K) ? w[(long)k * N + n] : 0.f;
  ushort_t h = f2bf(v);  float r1 = v - bf2f(h);
  ushort_t mm = f2bf(r1); float r2 = r1 - bf2f(mm);
  wTh[id] = h; wTm[id] = mm; wTl[id] = f2bf(r2);
}

// weight transpose + bf16 convert: w (K,N) fp32 -> wT (N,K) bf16
__global__ void wtrans_k(const float* __restrict__ w, ushort_t* __restrict__ wT,
                         int K, int N)
{
  int id = blockIdx.x * blockDim.x + threadIdx.x;
  if (id >= K * N) return;
  int k = id / N, n = id - k * N;
  wT[(long)n * K + k] = f2bf(w[id]);
}

// ======================= VQ =======================
__global__ __launch_bounds__(256) void vq_k(
    const float* __restrict__ Z, const float* __restrict__ cb,
    int* __restrict__ cidx, float* __restrict__ code_f,
    float* __restrict__ vq_accum, float inv_cnt)
{
  __shared__ __align__(16) float cbs[128 * 64];
  __shared__ float c2s[512];
  __shared__ float red[256];
  const int t = threadIdx.x;
  const int beat = blockIdx.x * 256 + t;

#pragma unroll
  for (int r = 0; r < 2; ++r) {
    int c = t + r * 256;
    float s = 0.f;
    for (int d = 0; d < 64; d += 4) {
      float4 v = *reinterpret_cast<const float4*>(&cb[(long)c * 64 + d]);
      s += v.x * v.x + v.y * v.y + v.z * v.z + v.w * v.w;
    }
    c2s[c] = s;
  }

  float z[64];
  float z2 = 0.f;
#pragma unroll
  for (int d = 0; d < 64; d += 4) {
    float4 v = *reinterpret_cast<const float4*>(&Z[(long)beat * 64 + d]);
    z[d] = v.x; z[d + 1] = v.y; z[d + 2] = v.z; z[d + 3] = v.w;
    z2 += v.x * v.x + v.y * v.y + v.z * v.z + v.w * v.w;
  }

  float best = 3.4e38f;
  int bi = 0;
  for (int c0 = 0; c0 < NCODES; c0 += 128) {
    __syncthreads();
#pragma unroll
    for (int i = 0; i < 8; ++i) {
      int idx = (t + i * 256) * 4;
      *reinterpret_cast<float4*>(&cbs[idx]) =
          *reinterpret_cast<const float4*>(&cb[(long)c0 * 64 + idx]);
    }
    __syncthreads();
    for (int c = 0; c < 128; ++c) {
      const float* cp = &cbs[c * 64];
      float d0 = 0.f, d1 = 0.f, d2 = 0.f, d3 = 0.f;
#pragma unroll
      for (int d = 0; d < 64; d += 4) {
        d0 += z[d] * cp[d];
        d1 += z[d + 1] * cp[d + 1];
        d2 += z[d + 2] * cp[d + 2];
        d3 += z[d + 3] * cp[d + 3];
      }
      float dist = z2 - 2.f * ((d0 + d1) + (d2 + d3)) + c2s[c0 + c];
      if (dist < best) { best = dist; bi = c0 + c; }
    }
  }
  cidx[beat] = bi;
  code_f[beat] = (float)bi;

  red[t] = best;
  __syncthreads();
  for (int s = 128; s > 0; s >>= 1) {
    if (t < s) red[t] += red[t + s];
    __syncthreads();
  }
  if (t == 0) atomicAdd(vq_accum, red[0] * inv_cnt);
}

__global__ void rhythm_k(const int* __restrict__ cidx, const int* __restrict__ rr,
                         const int* __restrict__ rrp, const float* __restrict__ hs,
                         const float* __restrict__ hc, const float* __restrict__ cemb,
                         const float* __restrict__ rremb, const float* __restrict__ rrpemb,
                         const float* __restrict__ hw, ushort_t* __restrict__ outh)
{
  int i = blockIdx.x * blockDim.x + threadIdx.x;
  if (i >= BM_ * RHY_D) return;
  int m = i >> 7, d = i & 127;
  float v = cemb[cidx[m] * RHY_D + d] + rremb[rr[m] * RHY_D + d] +
            rrpemb[rrp[m] * RHY_D + d] + hs[m] * hw[d] + hc[m] * hw[RHY_D + d];
  outh[i] = f2bf(gelu_t(v));
}

__global__ __launch_bounds__(512) void ep_mean_k(
    const ushort_t* __restrict__ ctxh, const ushort_t* __restrict__ rhyh,
    const int* __restrict__ neps, float* __restrict__ ctx_mean,
    float* __restrict__ rhy_mean)
{
  int be = blockIdx.x;
  int t = threadIdx.x;
  bool valid = (be & (E_ - 1)) < neps[be >> 7];
  if (t < EP_D) {
    float s = 0.f;
    for (int l = 0; l < EPL; ++l) s += bf2f(ctxh[((long)be * EPL + l) * EP_D + t]);
    ctx_mean[be * EP_D + t] = s * (1.0f / EPL);
  } else if (t < EP_D + RHY_D) {
    int d = t - EP_D;
    float s = 0.f;
    for (int l = 0; l < EPL; ++l) s += bf2f(rhyh[((long)be * EPL + l) * RHY_D + d]);
    rhy_mean[be * RHY_D + d] = valid ? s * (1.0f / EPL) : 0.f;
  }
}

__global__ __launch_bounds__(512) void day_k(const float* __restrict__ ec,
                                             const int* __restrict__ neps,
                                             float* __restrict__ day)
{
  int b = blockIdx.x, h = threadIdx.x;
  int n = neps[b];
  float s = 0.f;
  for (int e = 0; e < n; ++e) s += ec[((long)b * E_ + e) * DAY_D + h];
  day[b * DAY_D + h] = s / (float)(n > 0 ? n : 1);
}

extern "C" void kernel_launch(void* const* d_in, const int* in_sizes, int n_in,
                              void* d_out, int out_size, void* d_ws, size_t ws_size,
                              hipStream_t stream)
{
  (void)in_sizes; (void)n_in; (void)out_size; (void)ws_size;
  const float* windows  = (const float*)d_in[0];
  const float* metadata = (const float*)d_in[1];
  const int*   n_eps    = (const int*)d_in[3];
  const int*   rr_bins  = (const int*)d_in[4];
  const int*   rrp_bins = (const int*)d_in[5];
  const float* hour_sin = (const float*)d_in[6];
  const float* hour_cos = (const float*)d_in[7];
  const float* w_tok1 = (const float*)d_in[8];
  const float* b_tok1 = (const float*)d_in[9];
  const float* w_tok2 = (const float*)d_in[10];
  const float* b_tok2 = (const float*)d_in[11];
  const float* w_code = (const float*)d_in[12];
  const float* codebook = (const float*)d_in[13];
  const float* w_ep1 = (const float*)d_in[14];
  const float* b_ep1 = (const float*)d_in[15];
  const float* w_ep2 = (const float*)d_in[16];
  const float* b_ep2 = (const float*)d_in[17];
  const float* w_eptok = (const float*)d_in[18];
  const float* b_eptok = (const float*)d_in[19];
  const float* code_emb = (const float*)d_in[20];
  const float* rr_emb = (const float*)d_in[21];
  const float* rrp_emb = (const float*)d_in[22];
  const float* hour_w = (const float*)d_in[23];
  const float* w_fuse = (const float*)d_in[24];
  const float* b_fuse = (const float*)d_in[25];
  const float* w_day = (const float*)d_in[26];
  const float* b_day = (const float*)d_in[27];
  const float* w_bp1 = (const float*)d_in[28];
  const float* b_bp1 = (const float*)d_in[29];
  const float* w_bp2 = (const float*)d_in[30];
  const float* b_bp2 = (const float*)d_in[31];

  float* out = (float*)d_out;
  float* ws  = (float*)d_ws;

  // ---- workspace layout (float offsets; 64,421,888 floats total) ----
  // sizes: X plane = 65536x256 bf16 = 8,388,608 fl; H plane = 65536x512 bf16 =
  // 16,777,216 fl; BE fp32 = 16,777,216 fl; BEh = 8,388,608 fl; Z = 4,194,304 fl;
  // HEh/CTXh = 12,582,912 fl; RHYh = 4,194,304 fl; BPHh = 16,777,216 fl.
  //
  //  [0,  8.39M): Xh      -> BE[0,16.78M) at G2 (X dead after G1) -> BPHh[0,16.78M) at G6 (BE dead after G3)
  //  [8.39M, 16.78M): Xm      (absorbed by BE overlay)
  //  [16.78M, 25.17M): Xl  -> BEh at G2 (Xl dead after G1)
  //  [25.17M, 41.94M): Hh  -> Z [25.17M, 29.36M) at G3 (H dead after G2)
  //                        -> RHYh [29.36M, 33.55M) after vq
  //                        -> HEh [33.55M, 46.14M) at G4 (spans into Hm)
  //  [41.94M, 58.72M): Hm  -> CTXh [46.14M, 58.72M) at G5
  //  Hl lives in out[0, 16.78M) — beat_repr region, dead before G7 writes it.
  //  statics at S0 = 58,720,256.
  ushort_t* Xh   = (ushort_t*)ws;
  ushort_t* Xm   = (ushort_t*)(ws + 8388608L);
  ushort_t* Xl   = (ushort_t*)(ws + 16777216L);
  ushort_t* Hh   = (ushort_t*)(ws + 25165824L);
  ushort_t* Hm   = (ushort_t*)(ws + 41943040L);
  ushort_t* Hl   = (ushort_t*)out;                    // scratch; dead before G7
  float*    BE   = ws;                                // [0, 16.78M) over Xh/Xm
  ushort_t* BEh  = (ushort_t*)(ws + 16777216L);       // over Xl
  float*    Z    = ws + 25165824L;                    // over Hh-head
  ushort_t* RHYh = (ushort_t*)(ws + 29360128L);       // over Hh (after vq)
  ushort_t* HEh  = (ushort_t*)(ws + 33554432L);       // over Hh-tail/Hm-head
  ushort_t* CTXh = (ushort_t*)(ws + 46137344L);       // over Hm-tail (ends at S0)
  ushort_t* BPHh = (ushort_t*)ws;                     // over BE at G6

  const long S0 = 58720256L;
  ushort_t* w1Th = (ushort_t*)(ws + S0);              // 512x256 u each
  ushort_t* w1Tm = w1Th + 131072L;
  ushort_t* w1Tl = w1Th + 262144L;
  ushort_t* w2Th = w1Th + 393216L;                    // 256x512 u each
  ushort_t* w2Tm = w1Th + 524288L;
  ushort_t* w2Tl = w1Th + 655360L;                    // ends 786,432 u = 393,216 fl
  ushort_t* WT   = (ushort_t*)(ws + S0 + 393216L);    // 901,120 u = 450,560 fl
  int*      CIDX  = (int*)(ws + S0 + 843776L);        // 65,536
  float*    CMEAN = ws + S0 + 909312L;                // 1024x384
  float*    RMEAN = ws + S0 + 1302528L;               // 1024x128
  float*    EPW   = ws + S0 + 1433600L;               // 1024x384
  float*    FUSED = ws + S0 + 1826816L;               // 1024x512; ends S0+2,351,104

  ushort_t* wep1T = WT;                 // 384x256
  ushort_t* wep2T = WT + 98304L;        // 384x384
  ushort_t* wbp1T = WT + 245760L;       // 512x768
  ushort_t* wbp2T = WT + 638976L;       // 512x512

  hipMemsetAsync((void*)(out + OFF_VQ), 0, sizeof(float), stream);

  dim3 blk(256);
  // X split -> Xh/Xm/Xl (BM_ x 256, zero-padded 246..255)
  split_x3_k<<<dim3((BM_ * KP1) / 256), blk, 0, stream>>>(windows, metadata, Xh, Xm, Xl);
  // weight preps
  wsplit3_k<<<dim3((TOK_H * KP1 + 255) / 256), blk, 0, stream>>>(
      w_tok1, w1Th, w1Tm, w1Tl, WINF, TOK_H, KP1);
  wsplit3_k<<<dim3((BEAT_D * TOK_H + 255) / 256), blk, 0, stream>>>(
      w_tok2, w2Th, w2Tm, w2Tl, TOK_H, BEAT_D, TOK_H);
  wtrans_k<<<dim3((BEAT_D * EP_D + 255) / 256), blk, 0, stream>>>(w_ep1, wep1T, BEAT_D, EP_D);
  wtrans_k<<<dim3((EP_D * EP_D + 255) / 256), blk, 0, stream>>>(w_ep2, wep2T, EP_D, EP_D);
  wtrans_k<<<dim3((768 * DAY_D + 255) / 256), blk, 0, stream>>>(w_bp1, wbp1T, 768, DAY_D);
  wtrans_k<<<dim3((DAY_D * DAY_D + 255) / 256), blk, 0, stream>>>(w_bp2, wbp2T, DAY_D, DAY_D);
  // G1: H = gelu(X @ w_tok1 + b)  65536 x 256(pad) x 512, bf16x6 MFMA (fp32-class)
  //     -> Hh/Hm/Hl planes (Hl scratched into out[], dead before G7)
  gemm_split6<true, 0><<<dim3(TOK_H / 128, BM_ / 128), blk, 0, stream>>>(
      Xh, Xm, Xl, w1Th, w1Tm, w1Tl, b_tok1, Hh, Hm, Hl, nullptr, nullptr, TOK_H, KP1);
  // G2: BE = H @ w_tok2 + b  65536 x 512 x 256, bf16x6 MFMA (fp32-class)
  //     -> BE fp32 + BEh bf16  (matches reference association: BE then @ w_code)
  gemm_split6<false, 2><<<dim3(BEAT_D / 128, BM_ / 128), blk, 0, stream>>>(
      Hh, Hm, Hl, w2Th, w2Tm, w2Tl, b_tok2, nullptr, nullptr, nullptr, BE, BEh,
      BEAT_D, TOK_H);
  // G3: Z = BE @ w_code  (fp32 VALU, identical structure to the passing R0 kernel)
  gemm_k<0, false, false, false><<<dim3(1, BM_ / 128), blk, 0, stream>>>(
      BE, nullptr, nullptr, w_code, nullptr, Z, BM_, CODE_D, BEAT_D);
  // VQ (consumes Z)
  vq_k<<<dim3(BM_ / 256), blk, 0, stream>>>(Z, codebook, CIDX, out + OFF_CODE,
                                            out + OFF_VQ, 1.0f / (float)(BM_ * CODE_D));
  // rhythm -> bf16
  rhythm_k<<<dim3((BM_ * RHY_D) / 256), blk, 0, stream>>>(
      CIDX, rr_bins, rrp_bins, hour_sin, hour_cos, code_emb, rr_emb, rrp_emb, hour_w, RHYh);
  // G4: HEh = gelu(BEh @ w_ep1 + b)   bf16 MFMA, 65536 x 256 x 384
  gemm_bf16<0, true, false, 0><<<dim3(EP_D / 128, BM_ / 128), blk, 0, stream>>>(
      BEh, nullptr, nullptr, nullptr, wep1T, b_ep1, nullptr, HEh, EP_D, BEAT_D);
  // G5: CTXh = mask(HEh @ w_ep2 + b)  bf16 MFMA, 65536 x 384 x 384
  gemm_bf16<0, false, true, 0><<<dim3(EP_D / 128, BM_ / 128), blk, 0, stream>>>(
      HEh, nullptr, nullptr, n_eps, wep2T, b_ep2, nullptr, CTXh, EP_D, EP_D);
  // episode means from bf16
  ep_mean_k<<<dim3(B_ * E_), dim3(512), 0, stream>>>(CTXh, RHYh, n_eps, CMEAN, RMEAN);
  // E2: ep_wave = mask(CMEAN @ w_eptok + b)  fp32 small
  gemm_k<0, false, true, true><<<dim3(EP_D / 64, (B_ * E_) / 128), blk, 0, stream>>>(
      CMEAN, nullptr, n_eps, w_eptok, b_eptok, EPW, B_ * E_, EP_D, EP_D);
  // E3: FUSED = gelu([EPW|RMEAN] @ w_fuse + b)
  gemm_k<3, true, true, false><<<dim3(DAY_D / 64, (B_ * E_) / 128), blk, 0, stream>>>(
      EPW, RMEAN, nullptr, w_fuse, b_fuse, FUSED, B_ * E_, DAY_D, EP_D + RHY_D);
  // E4: episode_ctx = FUSED @ w_day + b -> out
  gemm_k<0, false, true, false><<<dim3(DAY_D / 64, (B_ * E_) / 128), blk, 0, stream>>>(
      FUSED, nullptr, nullptr, w_day, b_day, out + OFF_EPCTX, B_ * E_, DAY_D, DAY_D);
  // E5: day_embed
  day_k<<<dim3(B_), dim3(DAY_D), 0, stream>>>(out + OFF_EPCTX, n_eps, out + OFF_DAY);
  // G6: BPHh = gelu([BEh|CTXh|RHYh] @ w_bp1 + b)  bf16 MFMA, 65536 x 768 x 512
  gemm_bf16<1, true, false, 0><<<dim3(DAY_D / 128, BM_ / 128), blk, 0, stream>>>(
      BEh, CTXh, RHYh, nullptr, wbp1T, b_bp1, nullptr, BPHh, DAY_D, 768);
  // G7: beat_repr = BPHh @ w_bp2 + b -> out fp32, 65536 x 512 x 512
  //     (overwrites the Hl scratch region — Hl long dead)
  gemm_bf16<0, false, false, 1><<<dim3(DAY_D / 128, BM_ / 128), blk, 0, stream>>>(
      BPHh, nullptr, nullptr, nullptr, wbp2T, b_bp2, out, nullptr, DAY_D, DAY_D);
}

// Round 7
// 1513.417 us; speedup vs baseline: 1.3180x; 1.2215x over previous
//
#include <hip/hip_runtime.h>
#include <hip/hip_bf16.h>
#include <math.h>

// ---- problem constants ----
#define B_      8
#define M_      8192
#define E_      128
#define EPL     64
#define BM_     (B_ * M_)      // 65536 beats
#define BEAT_D  256
#define EP_D    384
#define RHY_D   128
#define DAY_D   512
#define NCODES  512
#define CODE_D  64
#define TOK_H   512
#define WINF    246
#define KP1     256            // padded K for G1 (246 -> 256)

// out layout (floats)
#define OFF_DAY   33554432L
#define OFF_EPCTX 33558528L
#define OFF_CODE  34082816L
#define OFF_VQ    34148352L

typedef unsigned short ushort_t;
typedef __attribute__((ext_vector_type(8))) short short8;
typedef __attribute__((ext_vector_type(4))) float floatx4;

__device__ __forceinline__ float gelu_t(float x) {
  float x3 = x * x * x;
  return 0.5f * x * (1.0f + tanhf(0.7978845608028654f * (x + 0.044715f * x3)));
}

__device__ __forceinline__ ushort_t f2bf(float f) {
  union { float f; unsigned u; } x; x.f = f;
  unsigned r = (x.u + 0x7fffu + ((x.u >> 16) & 1u)) >> 16;
  return (ushort_t)r;
}
__device__ __forceinline__ float bf2f(ushort_t u) {
  union { unsigned u; float f; } x; x.u = ((unsigned)u) << 16;
  return x.f;
}

// ======================= fp32 GEMM (small shapes) =======================
// A-source gather modes (fp32): 0: plain row-major, 3: ep_wave|ep_rhy
template<int AMODE>
__device__ __forceinline__ float load_A(const float* __restrict__ A,
                                        const float* __restrict__ A2,
                                        int m, int k, int K) {
  if (AMODE == 0) {
    return A[(long)m * K + k];
  } else {
    if (k < 384) return A[(long)m * 384 + k];
    return A2[(long)m * 128 + (k - 384)];
  }
}

// Small fp32 GEMM: tile 128x64, 8x4/thread. Used for G3/E2/E3/E4.
template<int AMODE, bool DOGELU, bool HASBIAS, bool EPMASK>
__global__ __launch_bounds__(256) void gemm_k(
    const float* __restrict__ A, const float* __restrict__ A2,
    const int* __restrict__ neps,
    const float* __restrict__ Bm, const float* __restrict__ bias,
    float* __restrict__ C, int M, int N, int K)
{
  __shared__ __align__(16) float As[16][132];
  __shared__ __align__(16) float Bs[16][68];

  const int bn = blockIdx.x * 64;
  const int bm = blockIdx.y * 128;
  const int tid = threadIdx.x;
  const int tx = tid & 15;
  const int ty = tid >> 4;

  float acc[8][4];
#pragma unroll
  for (int i = 0; i < 8; ++i)
#pragma unroll
    for (int j = 0; j < 4; ++j) acc[i][j] = 0.f;

  for (int k0 = 0; k0 < K; k0 += 16) {
    {
      int kk = tid & 15, r0 = tid >> 4;
      int gk = k0 + kk;
      bool kin = (gk < K);
#pragma unroll
      for (int i = 0; i < 8; ++i) {
        int row = r0 + i * 16;
        As[kk][row] = kin ? load_A<AMODE>(A, A2, bm + row, gk, K) : 0.f;
      }
    }
    {
      int c = tid & 63, r0 = tid >> 6;
#pragma unroll
      for (int i = 0; i < 4; ++i) {
        int kk = r0 + i * 4;
        int gk = k0 + kk;
        Bs[kk][c] = (gk < K) ? Bm[(long)gk * N + bn + c] : 0.f;
      }
    }
    __syncthreads();
#pragma unroll
    for (int kk = 0; kk < 16; ++kk) {
      float4 a0 = *reinterpret_cast<const float4*>(&As[kk][ty * 8]);
      float4 a1 = *reinterpret_cast<const float4*>(&As[kk][ty * 8 + 4]);
      float4 bv = *reinterpret_cast<const float4*>(&Bs[kk][tx * 4]);
      float av[8] = {a0.x, a0.y, a0.z, a0.w, a1.x, a1.y, a1.z, a1.w};
      float bb[4] = {bv.x, bv.y, bv.z, bv.w};
#pragma unroll
      for (int i = 0; i < 8; ++i)
#pragma unroll
        for (int j = 0; j < 4; ++j) acc[i][j] += av[i] * bb[j];
    }
    __syncthreads();
  }

#pragma unroll
  for (int i = 0; i < 8; ++i) {
    int gm = bm + ty * 8 + i;
    bool valid = true;
    if (EPMASK) valid = ((gm & (E_ - 1)) < neps[gm >> 7]);
    float4 o;
    float* op = &o.x;
#pragma unroll
    for (int j = 0; j < 4; ++j) {
      int gn = bn + tx * 4 + j;
      float v = acc[i][j];
      if (HASBIAS) v += bias[gn];
      if (DOGELU) v = gelu_t(v);
      if (EPMASK && !valid) v = 0.f;
      op[j] = v;
    }
    *reinterpret_cast<float4*>(&C[(long)gm * N + bn + tx * 4]) = o;
  }
}

// ======================= bf16 MFMA GEMM =======================
// C(MxN) = epi(A(MxK)_bf16 @ BT(NxK)_bf16 + bias). M%128==0, N%128==0, K%32==0.
// tile 128x128, 4 waves (2x2), each wave 64x64 via 4x4 mfma_f32_16x16x32_bf16.
// AMODE: 0 plain A; 1 concat [BEh(256)|CTXh(384)|RHYh(128)] (k0 never straddles).
// OUTM: 0 -> bf16 Ch; 1 -> fp32 C.
template<int AMODE, bool DOGELU, bool BEATMASK, int OUTM>
__global__ __launch_bounds__(256) void gemm_bf16(
    const ushort_t* __restrict__ A, const ushort_t* __restrict__ A2,
    const ushort_t* __restrict__ A3, const int* __restrict__ neps,
    const ushort_t* __restrict__ BT, const float* __restrict__ bias,
    float* __restrict__ C, ushort_t* __restrict__ Ch, int N, int K)
{
  __shared__ __align__(16) ushort_t As[128 * 40 + 8];
  __shared__ __align__(16) ushort_t Bs[128 * 40 + 8];

  const int bn = blockIdx.x * 128;
  const int bm = blockIdx.y * 128;
  const int tid = threadIdx.x;
  const int lane = tid & 63;
  const int wave = tid >> 6;
  const int wm = wave & 1;
  const int wn = wave >> 1;
  const int lm = lane & 15;
  const int q  = lane >> 4;

  floatx4 acc[4][4];
#pragma unroll
  for (int i = 0; i < 4; ++i)
#pragma unroll
    for (int j = 0; j < 4; ++j) acc[i][j] = (floatx4)0.f;

  for (int k0 = 0; k0 < K; k0 += 32) {
    const ushort_t* srcA; int ldA, cA;
    if (AMODE == 0) { srcA = A; ldA = K; cA = k0; }
    else {
      if (k0 < 256)      { srcA = A;  ldA = 256; cA = k0; }
      else if (k0 < 640) { srcA = A2; ldA = 384; cA = k0 - 256; }
      else               { srcA = A3; ldA = 128; cA = k0 - 640; }
    }
#pragma unroll
    for (int i = 0; i < 2; ++i) {
      int c = tid + i * 256;
      int r = c >> 2, h = c & 3;
      float4 v = *reinterpret_cast<const float4*>(&srcA[(long)(bm + r) * ldA + cA + h * 8]);
      *reinterpret_cast<float4*>(&As[r * 40 + h * 8]) = v;
    }
#pragma unroll
    for (int i = 0; i < 2; ++i) {
      int c = tid + i * 256;
      int r = c >> 2, h = c & 3;
      float4 v = *reinterpret_cast<const float4*>(&BT[(long)(bn + r) * K + k0 + h * 8]);
      *reinterpret_cast<float4*>(&Bs[r * 40 + h * 8]) = v;
    }
    __syncthreads();

    short8 af[4], bf[4];
#pragma unroll
    for (int i = 0; i < 4; ++i) {
      int mr = wm * 64 + i * 16 + lm;
      af[i] = *reinterpret_cast<const short8*>(&As[mr * 40 + q * 8]);
      int nr = wn * 64 + i * 16 + lm;
      bf[i] = *reinterpret_cast<const short8*>(&Bs[nr * 40 + q * 8]);
    }
#pragma unroll
    for (int i = 0; i < 4; ++i)
#pragma unroll
      for (int j = 0; j < 4; ++j)
        acc[i][j] = __builtin_amdgcn_mfma_f32_16x16x32_bf16(af[i], bf[j], acc[i][j], 0, 0, 0);
    __syncthreads();
  }

  // epilogue: C/D layout col = lane&15, row = q*4 + reg  [m89]
#pragma unroll
  for (int j = 0; j < 4; ++j) {
    int gn = bn + wn * 64 + j * 16 + lm;
    float bv = bias[gn];
#pragma unroll
    for (int i = 0; i < 4; ++i) {
#pragma unroll
      for (int r = 0; r < 4; ++r) {
        int gm = bm + wm * 64 + i * 16 + q * 4 + r;
        float v = acc[i][j][r] + bv;
        if (DOGELU) v = gelu_t(v);
        if (BEATMASK) {
          bool ok = (gm & (M_ - 1)) < neps[gm >> 13] * EPL;
          if (!ok) v = 0.f;
        }
        if (OUTM == 0) Ch[(long)gm * N + gn] = f2bf(v);
        else           C[(long)gm * N + gn] = v;
      }
    }
  }
}

// ======================= split-bf16 (3-plane, 6-product) MFMA GEMM =======================
// fp32-class precision on the matrix pipe:
//   x = xh + xm + xl (residual <= 2^-27);  C = hh + hm + mh + hl + mm + lh
// omitted terms (ml, lm, ll) <= ~2^-26 relative.
// OUTM 0: write THREE bf16 planes Oh/Om/Ol (stride N)            [G1]
// OUTM 2: write fp32 C (stride N) + bf16 Ch (stride N)           [G2]
template<bool DOGELU, int OUTM>
__global__ __launch_bounds__(256) void gemm_split6(
    const ushort_t* __restrict__ Ah, const ushort_t* __restrict__ Am,
    const ushort_t* __restrict__ Al,
    const ushort_t* __restrict__ BTh, const ushort_t* __restrict__ BTm,
    const ushort_t* __restrict__ BTl,
    const float* __restrict__ bias,
    ushort_t* __restrict__ Oh, ushort_t* __restrict__ Om, ushort_t* __restrict__ Ol,
    float* __restrict__ C, ushort_t* __restrict__ Ch,
    int N, int K)
{
  __shared__ __align__(16) ushort_t Ash[128 * 40];
  __shared__ __align__(16) ushort_t Asm[128 * 40];
  __shared__ __align__(16) ushort_t Asl[128 * 40];
  __shared__ __align__(16) ushort_t Bsh[128 * 40];
  __shared__ __align__(16) ushort_t Bsm[128 * 40];
  __shared__ __align__(16) ushort_t Bsl[128 * 40];

  const int bn = blockIdx.x * 128;
  const int bm = blockIdx.y * 128;
  const int tid = threadIdx.x;
  const int lane = tid & 63;
  const int wave = tid >> 6;
  const int wm = wave & 1;
  const int wn = wave >> 1;
  const int lm = lane & 15;
  const int q  = lane >> 4;

  floatx4 acc[4][4];
#pragma unroll
  for (int i = 0; i < 4; ++i)
#pragma unroll
    for (int j = 0; j < 4; ++j) acc[i][j] = (floatx4)0.f;

  for (int k0 = 0; k0 < K; k0 += 32) {
#pragma unroll
    for (int i = 0; i < 2; ++i) {
      int c = tid + i * 256;
      int r = c >> 2, h = c & 3;
      long aoff = (long)(bm + r) * K + k0 + h * 8;
      long boff = (long)(bn + r) * K + k0 + h * 8;
      *reinterpret_cast<float4*>(&Ash[r * 40 + h * 8]) =
          *reinterpret_cast<const float4*>(&Ah[aoff]);
      *reinterpret_cast<float4*>(&Asm[r * 40 + h * 8]) =
          *reinterpret_cast<const float4*>(&Am[aoff]);
      *reinterpret_cast<float4*>(&Asl[r * 40 + h * 8]) =
          *reinterpret_cast<const float4*>(&Al[aoff]);
      *reinterpret_cast<float4*>(&Bsh[r * 40 + h * 8]) =
          *reinterpret_cast<const float4*>(&BTh[boff]);
      *reinterpret_cast<float4*>(&Bsm[r * 40 + h * 8]) =
          *reinterpret_cast<const float4*>(&BTm[boff]);
      *reinterpret_cast<float4*>(&Bsl[r * 40 + h * 8]) =
          *reinterpret_cast<const float4*>(&BTl[boff]);
    }
    __syncthreads();

    short8 ah[4], am[4], al[4];
#pragma unroll
    for (int i = 0; i < 4; ++i) {
      int mr = wm * 64 + i * 16 + lm;
      ah[i] = *reinterpret_cast<const short8*>(&Ash[mr * 40 + q * 8]);
      am[i] = *reinterpret_cast<const short8*>(&Asm[mr * 40 + q * 8]);
      al[i] = *reinterpret_cast<const short8*>(&Asl[mr * 40 + q * 8]);
    }
#pragma unroll
    for (int j = 0; j < 4; ++j) {
      int nr = wn * 64 + j * 16 + lm;
      short8 bh = *reinterpret_cast<const short8*>(&Bsh[nr * 40 + q * 8]);
      short8 bmid = *reinterpret_cast<const short8*>(&Bsm[nr * 40 + q * 8]);
      short8 bl = *reinterpret_cast<const short8*>(&Bsl[nr * 40 + q * 8]);
#pragma unroll
      for (int i = 0; i < 4; ++i) {
        acc[i][j] = __builtin_amdgcn_mfma_f32_16x16x32_bf16(ah[i], bh,   acc[i][j], 0, 0, 0);
        acc[i][j] = __builtin_amdgcn_mfma_f32_16x16x32_bf16(ah[i], bmid, acc[i][j], 0, 0, 0);
        acc[i][j] = __builtin_amdgcn_mfma_f32_16x16x32_bf16(am[i], bh,   acc[i][j], 0, 0, 0);
        acc[i][j] = __builtin_amdgcn_mfma_f32_16x16x32_bf16(ah[i], bl,   acc[i][j], 0, 0, 0);
        acc[i][j] = __builtin_amdgcn_mfma_f32_16x16x32_bf16(am[i], bmid, acc[i][j], 0, 0, 0);
        acc[i][j] = __builtin_amdgcn_mfma_f32_16x16x32_bf16(al[i], bh,   acc[i][j], 0, 0, 0);
      }
    }
    __syncthreads();
  }

#pragma unroll
  for (int j = 0; j < 4; ++j) {
    int gn = bn + wn * 64 + j * 16 + lm;
    float bv = bias[gn];
#pragma unroll
    for (int i = 0; i < 4; ++i) {
#pragma unroll
      for (int r = 0; r < 4; ++r) {
        int gm = bm + wm * 64 + i * 16 + q * 4 + r;
        float v = acc[i][j][r] + bv;
        if (DOGELU) v = gelu_t(v);
        if (OUTM == 0) {
          ushort_t h = f2bf(v);  float r1 = v - bf2f(h);
          ushort_t mq = f2bf(r1); float r2 = r1 - bf2f(mq);
          Oh[(long)gm * N + gn] = h;
          Om[(long)gm * N + gn] = mq;
          Ol[(long)gm * N + gn] = f2bf(r2);
        } else {
          C[(long)gm * N + gn] = v;
          Ch[(long)gm * N + gn] = f2bf(v);
        }
      }
    }
  }
}

// split [windows|metadata] -> 3 bf16 planes (BM_, 256), cols 246..255 = 0
__global__ __launch_bounds__(256) void split_x3_k(
    const float* __restrict__ win, const float* __restrict__ meta,
    ushort_t* __restrict__ Xh, ushort_t* __restrict__ Xm, ushort_t* __restrict__ Xl)
{
  int i = blockIdx.x * 256 + threadIdx.x;   // over BM_ * 256
  int m = i >> 8, k = i & 255;
  float v = 0.f;
  if (k < 240)      v = win[(long)m * 240 + k];
  else if (k < 246) v = meta[(long)m * 6 + (k - 240)];
  ushort_t h = f2bf(v);  float r1 = v - bf2f(h);
  ushort_t mm = f2bf(r1); float r2 = r1 - bf2f(mm);
  Xh[i] = h; Xm[i] = mm; Xl[i] = f2bf(r2);
}

// transpose + 3-plane split: w (K,N) fp32 -> wTh/m/l (N,Kp) bf16, zero-pad k>=K
__global__ void wsplit3_k(const float* __restrict__ w,
                          ushort_t* __restrict__ wTh, ushort_t* __restrict__ wTm,
                          ushort_t* __restrict__ wTl, int K, int N, int Kp)
{
  int id = blockIdx.x * blockDim.x + threadIdx.x;
  if (id >= N * Kp) return;
  int n = id / Kp, k = id - n * Kp;
  float v = (k < K) ? w[(long)k * N + n] : 0.f;
  ushort_t h = f2bf(v);  float r1 = v - bf2f(h);
  ushort_t mm = f2bf(r1); float r2 = r1 - bf2f(mm);
  wTh[id] = h; wTm[id] = mm; wTl[id] = f2bf(r2);
}

// weight transpose + bf16 convert: w (K,N) fp32 -> wT (N,K) bf16
__global__ void wtrans_k(const float* __restrict__ w, ushort_t* __restrict__ wT,
                         int K, int N)
{
  int id = blockIdx.x * blockDim.x + threadIdx.x;
  if (id >= K * N) return;
  int k = id / N, n = id - k * N;
  wT[(long)n * K + k] = f2bf(w[id]);
}

// ======================= VQ =======================
// 1024 blocks x 256 thr; block = 64 beats, 4 waves split the 512 codes 4-ways.
// Per-(beat,code) distance arithmetic is bit-identical to the R5 kernel; the
// cross-wave merge uses (dist, idx) with lower-index tie-break, reproducing
// sequential first-argmin semantics exactly.
__global__ __launch_bounds__(256) void vq_k(
    const float* __restrict__ Z, const float* __restrict__ cb,
    int* __restrict__ cidx, float* __restrict__ code_f,
    float* __restrict__ vq_accum, float inv_cnt)
{
  __shared__ __align__(16) float cbs[128 * 64];
  __shared__ float c2s[512];
  __shared__ float mval[4][64];
  __shared__ int   midx[4][64];
  __shared__ float red[64];
  const int t = threadIdx.x;
  const int bt = t & 63;                 // beat within block
  const int q  = t >> 6;                 // wave id = code quarter
  const long beat = (long)blockIdx.x * 64 + bt;

#pragma unroll
  for (int r = 0; r < 2; ++r) {
    int c = t + r * 256;
    float s = 0.f;
    for (int d = 0; d < 64; d += 4) {
      float4 v = *reinterpret_cast<const float4*>(&cb[(long)c * 64 + d]);
      s += v.x * v.x + v.y * v.y + v.z * v.z + v.w * v.w;
    }
    c2s[c] = s;
  }

  float z[64];
  float z2 = 0.f;
#pragma unroll
  for (int d = 0; d < 64; d += 4) {
    float4 v = *reinterpret_cast<const float4*>(&Z[beat * 64 + d]);
    z[d] = v.x; z[d + 1] = v.y; z[d + 2] = v.z; z[d + 3] = v.w;
    z2 += v.x * v.x + v.y * v.y + v.z * v.z + v.w * v.w;
  }

  float best = 3.4e38f;
  int bi = 0;
  for (int c0 = 0; c0 < NCODES; c0 += 128) {
    __syncthreads();
#pragma unroll
    for (int i = 0; i < 8; ++i) {
      int idx = (t + i * 256) * 4;
      *reinterpret_cast<float4*>(&cbs[idx]) =
          *reinterpret_cast<const float4*>(&cb[(long)c0 * 64 + idx]);
    }
    __syncthreads();
    for (int c = q * 32; c < q * 32 + 32; ++c) {
      const float* cp = &cbs[c * 64];
      float d0 = 0.f, d1 = 0.f, d2 = 0.f, d3 = 0.f;
#pragma unroll
      for (int d = 0; d < 64; d += 4) {
        d0 += z[d] * cp[d];
        d1 += z[d + 1] * cp[d + 1];
        d2 += z[d + 2] * cp[d + 2];
        d3 += z[d + 3] * cp[d + 3];
      }
      float dist = z2 - 2.f * ((d0 + d1) + (d2 + d3)) + c2s[c0 + c];
      if (dist < best) { best = dist; bi = c0 + c; }
    }
  }
  mval[q][bt] = best;
  midx[q][bt] = bi;
  __syncthreads();
  if (q == 0) {
#pragma unroll
    for (int qq = 1; qq < 4; ++qq) {
      float v = mval[qq][bt];
      int ii = midx[qq][bt];
      if (v < best || (v == best && ii < bi)) { best = v; bi = ii; }
    }
    cidx[beat] = bi;
    code_f[beat] = (float)bi;
    red[bt] = best;
  }
  __syncthreads();
  for (int s = 32; s > 0; s >>= 1) {
    if (t < s) red[t] += red[t + s];
    __syncthreads();
  }
  if (t == 0) atomicAdd(vq_accum, red[0] * inv_cnt);
}

__global__ void rhythm_k(const int* __restrict__ cidx, const int* __restrict__ rr,
                         const int* __restrict__ rrp, const float* __restrict__ hs,
                         const float* __restrict__ hc, const float* __restrict__ cemb,
                         const float* __restrict__ rremb, const float* __restrict__ rrpemb,
                         const float* __restrict__ hw, ushort_t* __restrict__ outh)
{
  int i = blockIdx.x * blockDim.x + threadIdx.x;
  if (i >= BM_ * RHY_D) return;
  int m = i >> 7, d = i & 127;
  float v = cemb[cidx[m] * RHY_D + d] + rremb[rr[m] * RHY_D + d] +
            rrpemb[rrp[m] * RHY_D + d] + hs[m] * hw[d] + hc[m] * hw[RHY_D + d];
  outh[i] = f2bf(gelu_t(v));
}

__global__ __launch_bounds__(512) void ep_mean_k(
    const ushort_t* __restrict__ ctxh, const ushort_t* __restrict__ rhyh,
    const int* __restrict__ neps, float* __restrict__ ctx_mean,
    float* __restrict__ rhy_mean)
{
  int be = blockIdx.x;
  int t = threadIdx.x;
  bool valid = (be & (E_ - 1)) < neps[be >> 7];
  if (t < EP_D) {
    float s = 0.f;
    for (int l = 0; l < EPL; ++l) s += bf2f(ctxh[((long)be * EPL + l) * EP_D + t]);
    ctx_mean[be * EP_D + t] = s * (1.0f / EPL);
  } else if (t < EP_D + RHY_D) {
    int d = t - EP_D;
    float s = 0.f;
    for (int l = 0; l < EPL; ++l) s += bf2f(rhyh[((long)be * EPL + l) * RHY_D + d]);
    rhy_mean[be * RHY_D + d] = valid ? s * (1.0f / EPL) : 0.f;
  }
}

__global__ __launch_bounds__(512) void day_k(const float* __restrict__ ec,
                                             const int* __restrict__ neps,
                                             float* __restrict__ day)
{
  int b = blockIdx.x, h = threadIdx.x;
  int n = neps[b];
  float s = 0.f;
  for (int e = 0; e < n; ++e) s += ec[((long)b * E_ + e) * DAY_D + h];
  day[b * DAY_D + h] = s / (float)(n > 0 ? n : 1);
}

extern "C" void kernel_launch(void* const* d_in, const int* in_sizes, int n_in,
                              void* d_out, int out_size, void* d_ws, size_t ws_size,
                              hipStream_t stream)
{
  (void)in_sizes; (void)n_in; (void)out_size; (void)ws_size;
  const float* windows  = (const float*)d_in[0];
  const float* metadata = (const float*)d_in[1];
  const int*   n_eps    = (const int*)d_in[3];
  const int*   rr_bins  = (const int*)d_in[4];
  const int*   rrp_bins = (const int*)d_in[5];
  const float* hour_sin = (const float*)d_in[6];
  const float* hour_cos = (const float*)d_in[7];
  const float* w_tok1 = (const float*)d_in[8];
  const float* b_tok1 = (const float*)d_in[9];
  const float* w_tok2 = (const float*)d_in[10];
  const float* b_tok2 = (const float*)d_in[11];
  const float* w_code = (const float*)d_in[12];
  const float* codebook = (const float*)d_in[13];
  const float* w_ep1 = (const float*)d_in[14];
  const float* b_ep1 = (const float*)d_in[15];
  const float* w_ep2 = (const float*)d_in[16];
  const float* b_ep2 = (const float*)d_in[17];
  const float* w_eptok = (const float*)d_in[18];
  const float* b_eptok = (const float*)d_in[19];
  const float* code_emb = (const float*)d_in[20];
  const float* rr_emb = (const float*)d_in[21];
  const float* rrp_emb = (const float*)d_in[22];
  const float* hour_w = (const float*)d_in[23];
  const float* w_fuse = (const float*)d_in[24];
  const float* b_fuse = (const float*)d_in[25];
  const float* w_day = (const float*)d_in[26];
  const float* b_day = (const float*)d_in[27];
  const float* w_bp1 = (const float*)d_in[28];
  const float* b_bp1 = (const float*)d_in[29];
  const float* w_bp2 = (const float*)d_in[30];
  const float* b_bp2 = (const float*)d_in[31];

  float* out = (float*)d_out;
  float* ws  = (float*)d_ws;

  // ---- workspace layout (float offsets; 64,421,888 floats total) ----
  //  [0,  8.39M): Xh      -> BE[0,16.78M) at G2 (X dead after G1) -> BPHh[0,16.78M) at G6
  //  [8.39M, 16.78M): Xm      (absorbed by BE overlay)
  //  [16.78M, 25.17M): Xl  -> BEh at G2 (Xl dead after G1)
  //  [25.17M, 41.94M): Hh  -> Z [25.17M, 29.36M) at G3 (H dead after G2)
  //                        -> RHYh [29.36M, 33.55M) after vq
  //                        -> HEh [33.55M, 46.14M) at G4 (spans into Hm)
  //  [41.94M, 58.72M): Hm  -> CTXh [46.14M, 58.72M) at G5
  //  Hl lives in out[0, 16.78M) — beat_repr region, dead before G7 writes it.
  //  statics at S0 = 58,720,256.
  ushort_t* Xh   = (ushort_t*)ws;
  ushort_t* Xm   = (ushort_t*)(ws + 8388608L);
  ushort_t* Xl   = (ushort_t*)(ws + 16777216L);
  ushort_t* Hh   = (ushort_t*)(ws + 25165824L);
  ushort_t* Hm   = (ushort_t*)(ws + 41943040L);
  ushort_t* Hl   = (ushort_t*)out;                    // scratch; dead before G7
  float*    BE   = ws;                                // [0, 16.78M) over Xh/Xm
  ushort_t* BEh  = (ushort_t*)(ws + 16777216L);       // over Xl
  float*    Z    = ws + 25165824L;                    // over Hh-head
  ushort_t* RHYh = (ushort_t*)(ws + 29360128L);       // over Hh (after vq)
  ushort_t* HEh  = (ushort_t*)(ws + 33554432L);       // over Hh-tail/Hm-head
  ushort_t* CTXh = (ushort_t*)(ws + 46137344L);       // over Hm-tail (ends at S0)
  ushort_t* BPHh = (ushort_t*)ws;                     // over BE at G6

  const long S0 = 58720256L;
  ushort_t* w1Th = (ushort_t*)(ws + S0);              // 512x256 u each
  ushort_t* w1Tm = w1Th + 131072L;
  ushort_t* w1Tl = w1Th + 262144L;
  ushort_t* w2Th = w1Th + 393216L;                    // 256x512 u each
  ushort_t* w2Tm = w1Th + 524288L;
  ushort_t* w2Tl = w1Th + 655360L;                    // ends 786,432 u = 393,216 fl
  ushort_t* WT   = (ushort_t*)(ws + S0 + 393216L);    // 901,120 u = 450,560 fl
  int*      CIDX  = (int*)(ws + S0 + 843776L);        // 65,536
  float*    CMEAN = ws + S0 + 909312L;                // 1024x384
  float*    RMEAN = ws + S0 + 1302528L;               // 1024x128
  float*    EPW   = ws + S0 + 1433600L;               // 1024x384
  float*    FUSED = ws + S0 + 1826816L;               // 1024x512; ends S0+2,351,104

  ushort_t* wep1T = WT;                 // 384x256
  ushort_t* wep2T = WT + 98304L;        // 384x384
  ushort_t* wbp1T = WT + 245760L;       // 512x768
  ushort_t* wbp2T = WT + 638976L;       // 512x512

  hipMemsetAsync((void*)(out + OFF_VQ), 0, sizeof(float), stream);

  dim3 blk(256);
  // X split -> Xh/Xm/Xl (BM_ x 256, zero-padded 246..255)
  split_x3_k<<<dim3((BM_ * KP1) / 256), blk, 0, stream>>>(windows, metadata, Xh, Xm, Xl);
  // weight preps
  wsplit3_k<<<dim3((TOK_H * KP1 + 255) / 256), blk, 0, stream>>>(
      w_tok1, w1Th, w1Tm, w1Tl, WINF, TOK_H, KP1);
  wsplit3_k<<<dim3((BEAT_D * TOK_H + 255) / 256), blk, 0, stream>>>(
      w_tok2, w2Th, w2Tm, w2Tl, TOK_H, BEAT_D, TOK_H);
  wtrans_k<<<dim3((BEAT_D * EP_D + 255) / 256), blk, 0, stream>>>(w_ep1, wep1T, BEAT_D, EP_D);
  wtrans_k<<<dim3((EP_D * EP_D + 255) / 256), blk, 0, stream>>>(w_ep2, wep2T, EP_D, EP_D);
  wtrans_k<<<dim3((768 * DAY_D + 255) / 256), blk, 0, stream>>>(w_bp1, wbp1T, 768, DAY_D);
  wtrans_k<<<dim3((DAY_D * DAY_D + 255) / 256), blk, 0, stream>>>(w_bp2, wbp2T, DAY_D, DAY_D);
  // G1: H = gelu(X @ w_tok1 + b)  65536 x 256(pad) x 512, bf16x6 MFMA (fp32-class)
  //     -> Hh/Hm/Hl planes (Hl scratched into out[], dead before G7)
  gemm_split6<true, 0><<<dim3(TOK_H / 128, BM_ / 128), blk, 0, stream>>>(
      Xh, Xm, Xl, w1Th, w1Tm, w1Tl, b_tok1, Hh, Hm, Hl, nullptr, nullptr, TOK_H, KP1);
  // G2: BE = H @ w_tok2 + b  65536 x 512 x 256, bf16x6 MFMA (fp32-class)
  //     -> BE fp32 + BEh bf16  (matches reference association: BE then @ w_code)
  gemm_split6<false, 2><<<dim3(BEAT_D / 128, BM_ / 128), blk, 0, stream>>>(
      Hh, Hm, Hl, w2Th, w2Tm, w2Tl, b_tok2, nullptr, nullptr, nullptr, BE, BEh,
      BEAT_D, TOK_H);
  // G3: Z = BE @ w_code  (fp32 VALU, identical structure to the passing R0 kernel)
  gemm_k<0, false, false, false><<<dim3(1, BM_ / 128), blk, 0, stream>>>(
      BE, nullptr, nullptr, w_code, nullptr, Z, BM_, CODE_D, BEAT_D);
  // VQ (consumes Z) — 1024 blocks, 64 beats/block, 4-way code split
  vq_k<<<dim3(BM_ / 64), blk, 0, stream>>>(Z, codebook, CIDX, out + OFF_CODE,
                                           out + OFF_VQ, 1.0f / (float)(BM_ * CODE_D));
  // rhythm -> bf16
  rhythm_k<<<dim3((BM_ * RHY_D) / 256), blk, 0, stream>>>(
      CIDX, rr_bins, rrp_bins, hour_sin, hour_cos, code_emb, rr_emb, rrp_emb, hour_w, RHYh);
  // G4: HEh = gelu(BEh @ w_ep1 + b)   bf16 MFMA, 65536 x 256 x 384
  gemm_bf16<0, true, false, 0><<<dim3(EP_D / 128, BM_ / 128), blk, 0, stream>>>(
      BEh, nullptr, nullptr, nullptr, wep1T, b_ep1, nullptr, HEh, EP_D, BEAT_D);
  // G5: CTXh = mask(HEh @ w_ep2 + b)  bf16 MFMA, 65536 x 384 x 384
  gemm_bf16<0, false, true, 0><<<dim3(EP_D / 128, BM_ / 128), blk, 0, stream>>>(
      HEh, nullptr, nullptr, n_eps, wep2T, b_ep2, nullptr, CTXh, EP_D, EP_D);
  // episode means from bf16
  ep_mean_k<<<dim3(B_ * E_), dim3(512), 0, stream>>>(CTXh, RHYh, n_eps, CMEAN, RMEAN);
  // E2: ep_wave = mask(CMEAN @ w_eptok + b)  fp32 small
  gemm_k<0, false, true, true><<<dim3(EP_D / 64, (B_ * E_) / 128), blk, 0, stream>>>(
      CMEAN, nullptr, n_eps, w_eptok, b_eptok, EPW, B_ * E_, EP_D, EP_D);
  // E3: FUSED = gelu([EPW|RMEAN] @ w_fuse + b)
  gemm_k<3, true, true, false><<<dim3(DAY_D / 64, (B_ * E_) / 128), blk, 0, stream>>>(
      EPW, RMEAN, nullptr, w_fuse, b_fuse, FUSED, B_ * E_, DAY_D, EP_D + RHY_D);
  // E4: episode_ctx = FUSED @ w_day + b -> out
  gemm_k<0, false, true, false><<<dim3(DAY_D / 64, (B_ * E_) / 128), blk, 0, stream>>>(
      FUSED, nullptr, nullptr, w_day, b_day, out + OFF_EPCTX, B_ * E_, DAY_D, DAY_D);
  // E5: day_embed
  day_k<<<dim3(B_), dim3(DAY_D), 0, stream>>>(out + OFF_EPCTX, n_eps, out + OFF_DAY);
  // G6: BPHh = gelu([BEh|CTXh|RHYh] @ w_bp1 + b)  bf16 MFMA, 65536 x 768 x 512
  gemm_bf16<1, true, false, 0><<<dim3(DAY_D / 128, BM_ / 128), blk, 0, stream>>>(
      BEh, CTXh, RHYh, nullptr, wbp1T, b_bp1, nullptr, BPHh, DAY_D, 768);
  // G7: beat_repr = BPHh @ w_bp2 + b -> out fp32, 65536 x 512 x 512
  //     (overwrites the Hl scratch region — Hl long dead)
  gemm_bf16<0, false, false, 1><<<dim3(DAY_D / 128, BM_ / 128), blk, 0, stream>>>(
      BPHh, nullptr, nullptr, nullptr, wbp2T, b_bp2, out, nullptr, DAY_D, DAY_D);
}